// Round 2
// baseline (181.364 us; speedup 1.0000x reference)
//
#include <hip/hip_runtime.h>

// Series decomposition: T = moving_avg_C(x, k=25, replicate pad), xd = x - T,
// S = per-phase (c % 24) mean over G=14 groups of xd, R = xd - S.
// x: [B=32, C=336, HW=1024] fp32; outputs T,S,R.
//
// R5: store-granularity attack. R2/R3/R4 (occupancy, drain-removal, async
// staging) were all dead flat at ~175 us total -> the invariant is the store
// pattern: 128 B chunks per wave, ~16k concurrent DRAM row-streams, ~2.2 TB/s
// effective vs the 6.3 TB/s the (sequential) poison fill achieves on the same
// memory. Here: block = (b, 128-wide hw chunk), grid 256 = 1 block/CU.
// 512 threads = 4 channel-segments x 128 hw columns. Each thread WALKS its
// 84 channels with a running window sum (no x LDS staging; the 25-row
// trailing window sits in L1). Every wave-instruction is a 256 B contiguous
// run; a segment's two waves fill 512 B co-temporally; per step a block
// touches 4 rows of ONE tensor (pass 1: T only; pass 2: S,R) -> row-stream
// count drops ~16x. Seasonal sums accumulate into owner-exclusive LDS
// slices sv[seg][24][128]; pass 2 recomputes the window (free VALU, x
// re-reads hit L1/L2/L3, no extra HBM fetch) and emits S and R.

#define C_TOT   336
#define HWSZ    1024
#define PERIOD  24
#define GROUPS  14          // C_TOT / PERIOD
#define PAD     12          // (25-1)/2
#define KWIN    25
#define W       128         // hw span per block
#define NSEG    4
#define SEG_C   (C_TOT / NSEG)     // 84 channels per thread
#define NTHREADS (NSEG * W)        // 512 = 8 waves
#define NCHUNK  12                 // inner unroll: batch leading loads
#define NU      (SEG_C / NCHUNK)   // 7

__global__ __launch_bounds__(NTHREADS) void decomp_kernel(
    const float* __restrict__ x,
    float* __restrict__ outT,
    float* __restrict__ outS,
    float* __restrict__ outR)
{
    __shared__ float sv[NSEG][PERIOD][W];  // 48 KB per-segment phase partials
    __shared__ float sS[PERIOD][W];        // 12 KB final seasonal means

    const int tid = threadIdx.x;
    const int h   = tid & (W - 1);     // hw column; lanes of a wave -> 64 consecutive h
    const int s   = tid >> 7;          // channel segment 0..3
    const int b   = blockIdx.y;
    const int hw0 = blockIdx.x * W;
    const int c0  = s * SEG_C;         // 0, 84, 168, 252
    const float inv25 = 1.0f / (float)KWIN;
    const float inv14 = 1.0f / (float)GROUPS;

    const size_t base = (size_t)b * C_TOT * HWSZ + hw0 + h;
    const float* __restrict__ xb = x    + base;
    float* __restrict__ Tb       = outT + base;
    float* __restrict__ Sb       = outS + base;
    float* __restrict__ Rb       = outR + base;

    // Zero own sv cells (thread (s,h) is the exclusive owner of sv[s][*][h],
    // so no barrier is needed between init and accumulation).
    #pragma unroll
    for (int p = 0; p < PERIOD; ++p) sv[s][p][h] = 0.0f;

    // ---------------- Pass 1: T + phase accumulation ----------------
    {
        float winsum = 0.0f;
        #pragma unroll
        for (int d = -PAD; d <= PAD; ++d) {
            int cc = c0 + d;
            cc = cc < 0 ? 0 : (cc > C_TOT - 1 ? C_TOT - 1 : cc);
            winsum += xb[(size_t)cc * HWSZ];
        }
        int p = (s & 1) * PAD;         // (84*s) % 24 = 0 or 12
        for (int u = 0; u < NU; ++u) {
            float lead[NCHUNK], xc[NCHUNK], trail[NCHUNK];
            #pragma unroll
            for (int i = 0; i < NCHUNK; ++i) {
                const int c   = c0 + u * NCHUNK + i;
                const int chi = (c + 1 + PAD > C_TOT - 1) ? C_TOT - 1 : c + 1 + PAD;
                const int clo = (c - PAD < 0) ? 0 : c - PAD;
                lead[i]  = xb[(size_t)chi * HWSZ];   // leading edge: the HBM stream
                trail[i] = xb[(size_t)clo * HWSZ];   // trailing edge: L1 hit
                xc[i]    = xb[(size_t)c   * HWSZ];   // center: L1 hit
            }
            #pragma unroll
            for (int i = 0; i < NCHUNK; ++i) {
                const int c = c0 + u * NCHUNK + i;
                const float tval = winsum * inv25;
                const float xd   = xc[i] - tval;
                __builtin_nontemporal_store(tval, &Tb[(size_t)c * HWSZ]);
                sv[s][p][h] += xd;                   // owner-exclusive RMW
                winsum += lead[i] - trail[i];
                p = (p == PERIOD - 1) ? 0 : p + 1;
            }
        }
    }
    __syncthreads();                   // sv complete

    // ---------------- Cross-segment phase reduction ----------------
    #pragma unroll
    for (int k = 0; k < (PERIOD * W) / NTHREADS; ++k) {   // 6 items/thread
        const int idx = tid + k * NTHREADS;
        const int pp  = idx >> 7;          // / W
        const int hh  = idx & (W - 1);
        sS[pp][hh] = (sv[0][pp][hh] + sv[1][pp][hh] +
                      sv[2][pp][hh] + sv[3][pp][hh]) * inv14;
    }
    __syncthreads();                   // sS visible

    // ---------------- Pass 2: recompute T/xd, emit S and R ----------------
    {
        float winsum = 0.0f;
        #pragma unroll
        for (int d = -PAD; d <= PAD; ++d) {
            int cc = c0 + d;
            cc = cc < 0 ? 0 : (cc > C_TOT - 1 ? C_TOT - 1 : cc);
            winsum += xb[(size_t)cc * HWSZ];
        }
        int p = (s & 1) * PAD;
        for (int u = 0; u < NU; ++u) {
            float lead[NCHUNK], xc[NCHUNK], trail[NCHUNK];
            #pragma unroll
            for (int i = 0; i < NCHUNK; ++i) {
                const int c   = c0 + u * NCHUNK + i;
                const int chi = (c + 1 + PAD > C_TOT - 1) ? C_TOT - 1 : c + 1 + PAD;
                const int clo = (c - PAD < 0) ? 0 : c - PAD;
                lead[i]  = xb[(size_t)chi * HWSZ];   // all L1/L2/L3 hits now
                trail[i] = xb[(size_t)clo * HWSZ];
                xc[i]    = xb[(size_t)c   * HWSZ];
            }
            #pragma unroll
            for (int i = 0; i < NCHUNK; ++i) {
                const int c = c0 + u * NCHUNK + i;
                const float tval = winsum * inv25;
                const float xd   = xc[i] - tval;
                const float sval = sS[p][h];
                __builtin_nontemporal_store(sval,      &Sb[(size_t)c * HWSZ]);
                __builtin_nontemporal_store(xd - sval, &Rb[(size_t)c * HWSZ]);
                winsum += lead[i] - trail[i];
                p = (p == PERIOD - 1) ? 0 : p + 1;
            }
        }
    }
}

extern "C" void kernel_launch(void* const* d_in, const int* in_sizes, int n_in,
                              void* d_out, int out_size, void* d_ws, size_t ws_size,
                              hipStream_t stream) {
    const float* x = (const float*)d_in[0];
    // d_in[1] = kernel_size (25), d_in[2] = pe (24): fixed by setup, compiled in.
    float* out = (float*)d_out;
    const size_t N = (size_t)32 * C_TOT * HWSZ;  // 11,010,048 per output tensor

    dim3 grid(HWSZ / W, 32);  // (8 hw chunks, 32 batches) = 256 blocks = 1/CU
    decomp_kernel<<<grid, NTHREADS, 0, stream>>>(x, out, out + N, out + 2 * N);
}

// Round 3
// 174.914 us; speedup vs baseline: 1.0369x; 1.0369x over previous
//
#include <hip/hip_runtime.h>

// Series decomposition: T = moving_avg_C(x, k=25, replicate pad), xd = x - T,
// S = per-phase (c % 24) mean over G=14 groups of xd, R = xd - S.
// x: [B=32, C=336, HW=1024] fp32; outputs T,S,R.
//
// R6: single-variable A/B vs R4 -- non-temporal stores replaced by PLAIN
// stores. Evidence: four structurally different kernels (R2-R5: occupancy,
// drain-removal, async staging, long-run stores) all pinned at ~80 us kernel
// time (2.2 TB/s effective), while the harness's own fillBuffer sustains
// 6.35 TB/s pure-write on the same memory WITH PLAIN STORES and
// FETCH_SIZE=14.5 KB (i.e. full-line plain stores do NOT read-for-ownership
// on gfx950). The only store-path invariant across R2-R5 was
// __builtin_nontemporal_store on all 132 MB of output; hypothesis: the nt
// hint bypasses L2/L3 write-combining and drains at ~1.8 TB/s regardless of
// access structure. Everything else here is byte-identical to R4.

#define C_TOT 336
#define HWSZ 1024
#define PERIOD 24
#define GROUPS 14         // C_TOT / PERIOD
#define PAD 12            // (25-1)/2
#define W 32              // hw tile width (floats) -> 128 B rows
#define SEG_C 12          // channels per thread
#define NSEG 28           // C_TOT / SEG_C
#define NTHREADS (NSEG * W)   // 896 = 14 waves

__device__ __forceinline__ void gload_lds16(const float4* g, float4* l) {
    // LDS dest is wave-uniform base + lane*16; our idx is lane-contiguous
    // per wave (idx = 64*w + ... + lane), so linear layout is preserved.
    __builtin_amdgcn_global_load_lds(
        (const __attribute__((address_space(1))) unsigned int*)g,
        (__attribute__((address_space(3))) unsigned int*)l,
        16, 0, 0);
}

__global__ __launch_bounds__(NTHREADS, 8) void decomp_kernel(
    const float* __restrict__ x,
    float* __restrict__ outT,
    float* __restrict__ outS,
    float* __restrict__ outR)
{
    __shared__ float sx[C_TOT][W];     // 43008 B; bank = col -> 2-way max (free)
    __shared__ float sv[PERIOD][W];    // 3072 B

    const int tid = threadIdx.x;
    const int b   = blockIdx.y;
    const int hw0 = blockIdx.x * W;

    // ---- Stage x[b, :, hw0:hw0+32] -> LDS via global_load_lds (16 B) ----
    const float4* __restrict__ xg =
        (const float4*)(x + (size_t)b * C_TOT * HWSZ + hw0);
    float4* sx4 = (float4*)sx;
    #pragma unroll
    for (int k = 0; k < 3; ++k) {
        const int idx = tid + k * NTHREADS;                  // 0..2687
        gload_lds16(xg + (idx >> 3) * (HWSZ / 4) + (idx & 7), sx4 + idx);
    }
    asm volatile("s_waitcnt vmcnt(0)" ::: "memory");
    __syncthreads();                    // barrier 1: staging visible

    const int col = tid & (W - 1);
    const int seg = tid >> 5;          // 0..27
    const int c0  = seg * SEG_C;       // 0..324
    const float inv25 = 1.0f / 25.0f;
    const float inv14 = 1.0f / (float)GROUPS;

    // ---- Window prologue: sum of x[c0-12 .. c0+12], two independent chains ----
    float wa = 0.0f, wb = 0.0f;
    #pragma unroll
    for (int d = -PAD; d <= PAD; d += 2) {
        int cc = c0 + d;
        cc = cc < 0 ? 0 : cc; cc = cc > C_TOT - 1 ? C_TOT - 1 : cc;
        wa += sx[cc][col];
    }
    #pragma unroll
    for (int d = -PAD + 1; d <= PAD; d += 2) {
        int cc = c0 + d;
        cc = cc < 0 ? 0 : cc; cc = cc > C_TOT - 1 ? C_TOT - 1 : cc;
        wb += sx[cc][col];
    }
    float winsum = wa + wb;

    // ---- Window pass: T kept in registers only (NO stores here) ----
    float tval[SEG_C];
    #pragma unroll
    for (int j = 0; j < SEG_C; ++j) {
        const int c = c0 + j;
        tval[j] = winsum * inv25;
        int chi = c + 1 + PAD; chi = chi > C_TOT - 1 ? C_TOT - 1 : chi;
        int clo = c - PAD;     clo = clo < 0 ? 0 : clo;
        winsum += sx[chi][col] - sx[clo][col];
    }
    __syncthreads();                    // barrier 2: all window reads of sx done
                                        // (no vmem outstanding -> free drain)

    // ---- Overwrite sx with xd in-place (each (c,col) owned by one thread) ----
    #pragma unroll
    for (int j = 0; j < SEG_C; ++j) {
        const int c = c0 + j;
        sx[c][col] = sx[c][col] - tval[j];
    }
    __syncthreads();                    // barrier 3: xd visible

    // ---- Cross-group phase reduction ----
    if (tid < PERIOD * W) {             // 768 items; waves 12-13 idle (uniform)
        const int p = tid >> 5, cc = tid & (W - 1);
        float s = 0.0f;
        #pragma unroll
        for (int g = 0; g < GROUPS; ++g) s += sx[g * PERIOD + p][cc];
        sv[p][cc] = s * inv14;
    }
    __syncthreads();                    // barrier 4: sv visible

    // ---- Epilogue: ALL global stores (PLAIN, not nt), async retire ----
    const size_t base = (size_t)b * C_TOT * HWSZ + hw0 + col;
    float* __restrict__ Tb = outT + base;
    float* __restrict__ Sb = outS + base;
    float* __restrict__ Rb = outR + base;
    const int pbase = (seg & 1) * SEG_C;   // phase of channel c0+j is pbase + j
    #pragma unroll
    for (int j = 0; j < SEG_C; ++j) {
        const int c = c0 + j;
        const float s  = sv[pbase + j][col];
        const float xd = sx[c][col];
        Tb[(size_t)c * HWSZ] = tval[j];
        Sb[(size_t)c * HWSZ] = s;
        Rb[(size_t)c * HWSZ] = xd - s;
    }
}

extern "C" void kernel_launch(void* const* d_in, const int* in_sizes, int n_in,
                              void* d_out, int out_size, void* d_ws, size_t ws_size,
                              hipStream_t stream) {
    const float* x = (const float*)d_in[0];
    // d_in[1] = kernel_size (25), d_in[2] = pe (24): fixed by setup, compiled in.
    float* out = (float*)d_out;
    const size_t N = (size_t)32 * C_TOT * HWSZ;  // 11,010,048 per output tensor

    dim3 grid(HWSZ / W, 32);  // (32 hw tiles, 32 batches) = 1024 blocks
    decomp_kernel<<<grid, NTHREADS, 0, stream>>>(x, out, out + N, out + 2 * N);
}